// Round 9
// baseline (82.111 us; speedup 1.0000x reference)
//
#include <hip/hip_runtime.h>
#include <hip/hip_fp16.h>

#define N_NODES 100000
#define N_EDGES 600000
#define DIM 128
#define HID 64
#define NCHUNK 1563          // ceil(100000 / 64)

typedef __attribute__((ext_vector_type(8))) _Float16 half8;
typedef __attribute__((ext_vector_type(4))) _Float16 half4v;
typedef __attribute__((ext_vector_type(4))) float floatx4;

// direct global -> LDS, 16 B per lane (dest must be lane-linear!)
__device__ __forceinline__ void gload_lds16(const void* g, void* l) {
    __builtin_amdgcn_global_load_lds(
        (const __attribute__((address_space(1))) void*)g,
        (__attribute__((address_space(3))) void*)l, 16, 0, 0);
}

// ---------------------------------------------------------------------------
// Kernel 0: W1T[c][k] (f16, [128][128]) = c<64 ? W1[k][c] : W1[128+k][c-64]
// ---------------------------------------------------------------------------
__global__ __launch_bounds__(256) void prep_W(
    const float* __restrict__ W1, __half* __restrict__ W1T)
{
    const int o = (int)(blockIdx.x * blockDim.x + threadIdx.x) * 2;
    if (o >= 128 * 128) return;
    const int c = o >> 7, k = o & 127;
    float w0, w1;
    if (c < HID) { w0 = W1[k * HID + c];               w1 = W1[(k + 1) * HID + c]; }
    else         { w0 = W1[(DIM + k) * HID + c - HID]; w1 = W1[(DIM + k + 1) * HID + c - HID]; }
    W1T[o]     = __float2half(w0);
    W1T[o + 1] = __float2half(w1);
}

// ---------------------------------------------------------------------------
// Kernel 1 (R5 version, x2 internal repeat for counter capture): idempotent.
// ---------------------------------------------------------------------------
__global__ __launch_bounds__(256, 2) void precompute_P(
    const float* __restrict__ node_emb,
    const __half* __restrict__ W1T,
    const float* __restrict__ b1,
    __half* __restrict__ P)
{
    __shared__ float Abuf[2][64 * 128];          // 2 x 32 KB

    const int tid  = threadIdx.x;
    const int w    = tid >> 6;
    const int lane = tid & 63;
    const int lr   = lane & 15;
    const int q    = lane >> 4;

    half8 wf[8][4];
#pragma unroll
    for (int nt = 0; nt < 8; nt++)
#pragma unroll
        for (int ks = 0; ks < 4; ks++)
            wf[nt][ks] = *(const half8*)(W1T + (size_t)(nt * 16 + lr) * 128 + ks * 32 + q * 8);

    float bias_[4][4];
#pragma unroll
    for (int nt = 0; nt < 4; nt++) {
        const float4 b4 = *(const float4*)(b1 + nt * 16 + q * 4);
        bias_[nt][0] = b4.x; bias_[nt][1] = b4.y;
        bias_[nt][2] = b4.z; bias_[nt][3] = b4.w;
    }

    const int r8   = tid >> 5;
    const int in16 = (tid & 31) << 4;
    const char* nb = (const char*)node_emb;

    for (int rep = 0; rep < 2; rep++) {          // DIAGNOSTIC repeat
        int c = (int)blockIdx.x;
#pragma unroll
        for (int r = 0; r < 8; r++) {
            int row_in = r * 8 + r8;
            int grow = c * 64 + row_in;
            if (grow >= N_NODES) grow = N_NODES - 1;
            const size_t src = (size_t)grow * 512 + (size_t)(in16 ^ ((row_in & 7) << 4));
            gload_lds16(nb + src, (char*)&Abuf[0][0] + (r * 4096 + tid * 16));
        }

        int cur = 0;
        for (; c < NCHUNK; c += (int)gridDim.x, cur ^= 1) {
            const int cnext = c + (int)gridDim.x;
            if (cnext < NCHUNK) {
#pragma unroll
                for (int r = 0; r < 8; r++) {
                    int row_in = r * 8 + r8;
                    int grow = cnext * 64 + row_in;
                    if (grow >= N_NODES) grow = N_NODES - 1;
                    const size_t src = (size_t)grow * 512 + (size_t)(in16 ^ ((row_in & 7) << 4));
                    gload_lds16(nb + src, (char*)&Abuf[cur ^ 1][0] + (r * 4096 + tid * 16));
                }
                asm volatile("s_waitcnt vmcnt(8)" ::: "memory");
            } else {
                asm volatile("s_waitcnt vmcnt(0)" ::: "memory");
            }
            __builtin_amdgcn_s_barrier();

            floatx4 acc[8];
#pragma unroll
            for (int nt = 0; nt < 8; nt++) acc[nt] = (floatx4){0.f, 0.f, 0.f, 0.f};

            const char* Ab = (const char*)&Abuf[cur][0];
            const int rb = w * 16 + lr;
            const int sw = (rb & 7) << 4;
#pragma unroll
            for (int ks = 0; ks < 4; ks++) {
                const int cb = ks * 128 + q * 32;
                const float4 x0 = *(const float4*)(Ab + rb * 512 + ((cb)      ^ sw));
                const float4 x1 = *(const float4*)(Ab + rb * 512 + ((cb + 16) ^ sw));
                half8 af;
                af[0] = (_Float16)x0.x; af[1] = (_Float16)x0.y;
                af[2] = (_Float16)x0.z; af[3] = (_Float16)x0.w;
                af[4] = (_Float16)x1.x; af[5] = (_Float16)x1.y;
                af[6] = (_Float16)x1.z; af[7] = (_Float16)x1.w;
#pragma unroll
                for (int nt = 0; nt < 8; nt++)
                    acc[nt] = __builtin_amdgcn_mfma_f32_16x16x32_f16(wf[nt][ks], af, acc[nt], 0, 0, 0);
            }

            const int grow = c * 64 + w * 16 + lr;
            if (grow < N_NODES) {
                char* prow = (char*)P + (size_t)grow * 256;
#pragma unroll
                for (int m = 0; m < 4; m++) {
                    half8 hh;
#pragma unroll
                    for (int i = 0; i < 4; i++) {
                        float va = acc[2 * m][i];
                        float vb = acc[2 * m + 1][i];
                        if (m < 2) { va += bias_[2 * m][i]; vb += bias_[2 * m + 1][i]; }
                        hh[i]     = (_Float16)va;
                        hh[i + 4] = (_Float16)vb;
                    }
                    *(half8*)(prow + m * 64 + q * 16) = hh;
                }
            }
            __builtin_amdgcn_s_barrier();
        }
    }
}

// ---------------------------------------------------------------------------
__device__ inline bool detect_int64(const int* e32) {
    int orv = 0;
#pragma unroll
    for (int k = 0; k < 8; k++) orv |= e32[2 * k + 1];
    return orv == 0;
}

// ---------------------------------------------------------------------------
// Kernel 2 (R5 version, x2 internal repeat for counter capture): idempotent.
// ---------------------------------------------------------------------------
__global__ __launch_bounds__(256) void edge_mlp(
    const __half* __restrict__ P,
    const void* __restrict__ eidx_raw,
    const float* __restrict__ W2,
    const float* __restrict__ b2,
    float* __restrict__ out)
{
    const int* e32 = (const int*)eidx_raw;
    const long long* e64 = (const long long*)eidx_raw;
    const bool is64 = detect_int64(e32);

    const int tid  = threadIdx.x;
    const int lane = tid & 63;
    const int j    = lane & 15;
    const int grp  = lane >> 4;
    const int hbase = ((j >> 3) << 5) + ((j & 1) << 4) + (((j >> 1) & 3) << 2);
    const float4 w2 = *(const float4*)(W2 + hbase);
    const float b2v = b2[0];

    const int gwid   = (int)((blockIdx.x * blockDim.x + tid) >> 6);
    const int nwaves = (int)((gridDim.x * blockDim.x) >> 6);

    const half4v zero = {(_Float16)0, (_Float16)0, (_Float16)0, (_Float16)0};

    for (int rep = 0; rep < 2; rep++) {          // DIAGNOSTIC repeat
        for (int base = gwid * 16; base < N_EDGES; base += nwaves * 16) {
            int s[4], d[4];
#pragma unroll
            for (int u = 0; u < 4; u++) {
                const int e = base + 4 * u + grp;
                if (is64) { s[u] = (int)e64[e]; d[u] = (int)e64[N_EDGES + e]; }
                else      { s[u] = e32[e];      d[u] = e32[N_EDGES + e]; }
            }
            half4v av[4], bv[4];
#pragma unroll
            for (int u = 0; u < 4; u++) {
                av[u] = *(const half4v*)(P + (size_t)s[u] * 128 + 4 * j);
                bv[u] = *(const half4v*)(P + (size_t)d[u] * 128 + 64 + 4 * j);
            }
#pragma unroll
            for (int u = 0; u < 4; u++) {
                const half4v t = av[u] + bv[u];
                const half4v r = __builtin_elementwise_max(t, zero);
                float acc = (float)r[0] * w2.x + (float)r[1] * w2.y
                          + (float)r[2] * w2.z + (float)r[3] * w2.w;
#pragma unroll
                for (int off = 8; off >= 1; off >>= 1)
                    acc += __shfl_xor(acc, off, 64);
                if (j == 0) out[base + 4 * u + grp] = acc + b2v;
            }
        }
    }
}

// ---------------------------------------------------------------------------
// Fallback (ws too small): direct per-edge compute, slow but correct.
// ---------------------------------------------------------------------------
__global__ __launch_bounds__(256) void edge_mlp_direct(
    const float* __restrict__ node_emb,
    const void* __restrict__ eidx_raw,
    const float* __restrict__ W1,
    const float* __restrict__ b1,
    const float* __restrict__ W2,
    const float* __restrict__ b2,
    float* __restrict__ out)
{
    const int* e32 = (const int*)eidx_raw;
    const long long* e64 = (const long long*)eidx_raw;
    const bool is64 = detect_int64(e32);

    const int lane = threadIdx.x & 63;
    const float w2  = W2[lane];
    const float b2v = b2[0];
    const int gwid   = (int)((blockIdx.x * blockDim.x + threadIdx.x) >> 6);
    const int nwaves = (int)((gridDim.x * blockDim.x) >> 6);

    for (int e = gwid; e < N_EDGES; e += nwaves) {
        int s, d;
        if (is64) { s = (int)e64[e]; d = (int)e64[N_EDGES + e]; }
        else      { s = e32[e];      d = e32[N_EDGES + e]; }
        const float* es = node_emb + (size_t)s * DIM;
        const float* ed = node_emb + (size_t)d * DIM;
        float acc = b1[lane];
        for (int k = 0; k < DIM; k++) {
            acc += es[k] * W1[k * HID + lane];
            acc += ed[k] * W1[(DIM + k) * HID + lane];
        }
        float t = fmaxf(acc, 0.f) * w2;
#pragma unroll
        for (int off = 32; off >= 1; off >>= 1)
            t += __shfl_xor(t, off, 64);
        if (lane == 0) out[e] = t + b2v;
    }
}

// ---------------------------------------------------------------------------
// COUNTER-CAPTURE ROUND: both kernels do x2 internal repeats (idempotent) so
// each dispatch exceeds the 40us fillBuffer cutoff and shows up in the
// rocprof top-5 WITH counters. Next round removes the repeats.
// ---------------------------------------------------------------------------
extern "C" void kernel_launch(void* const* d_in, const int* in_sizes, int n_in,
                              void* d_out, int out_size, void* d_ws, size_t ws_size,
                              hipStream_t stream) {
    const float* node_emb = (const float*)d_in[0];
    const void*  eidx     = d_in[1];
    const float* W1       = (const float*)d_in[2];
    const float* b1       = (const float*)d_in[3];
    const float* W2       = (const float*)d_in[4];
    const float* b2       = (const float*)d_in[5];
    float* out = (float*)d_out;

    const size_t wt_off = 32u * 1024 * 1024;
    const size_t need   = wt_off + 128 * 128 * sizeof(__half);

    if (ws_size >= need) {
        __half* P   = (__half*)d_ws;
        __half* W1T = (__half*)((char*)d_ws + wt_off);
        prep_W<<<32, 256, 0, stream>>>(W1, W1T);
        precompute_P<<<512, 256, 0, stream>>>(node_emb, W1T, b1, P);
        edge_mlp<<<2048, 256, 0, stream>>>(P, eidx, W2, b2, out);
    } else {
        edge_mlp_direct<<<4096, 256, 0, stream>>>(node_emb, eidx, W1, b1, W2, b2, out);
    }
}

// Round 10
// 63.429 us; speedup vs baseline: 1.2945x; 1.2945x over previous
//
#include <hip/hip_runtime.h>
#include <hip/hip_fp16.h>

#define N_NODES 100000
#define N_EDGES 600000
#define DIM 128
#define HID 64
#define NCHUNK 1563          // ceil(100000 / 64)

typedef __attribute__((ext_vector_type(8))) _Float16 half8;
typedef __attribute__((ext_vector_type(4))) _Float16 half4v;
typedef __attribute__((ext_vector_type(4))) float floatx4;
typedef __attribute__((ext_vector_type(4))) unsigned int uint4v;

// direct global -> LDS, 16 B per lane (dest must be lane-linear!)
__device__ __forceinline__ void gload_lds16(const void* g, void* l) {
    __builtin_amdgcn_global_load_lds(
        (const __attribute__((address_space(1))) void*)g,
        (__attribute__((address_space(3))) void*)l, 16, 0, 0);
}

// ---------------------------------------------------------------------------
// Kernel 0: W1T[c][k] (f16, [128][128]) = c<64 ? W1[k][c] : W1[128+k][c-64]
// ---------------------------------------------------------------------------
__global__ __launch_bounds__(256) void prep_W(
    const float* __restrict__ W1, __half* __restrict__ W1T)
{
    const int o = (int)(blockIdx.x * blockDim.x + threadIdx.x) * 2;
    if (o >= 128 * 128) return;
    const int c = o >> 7, k = o & 127;
    float w0, w1;
    if (c < HID) { w0 = W1[k * HID + c];               w1 = W1[(k + 1) * HID + c]; }
    else         { w0 = W1[(DIM + k) * HID + c - HID]; w1 = W1[(DIM + k + 1) * HID + c - HID]; }
    W1T[o]     = __float2half(w0);
    W1T[o + 1] = __float2half(w1);
}

// ---------------------------------------------------------------------------
// Kernel 1 (R5 structure + wf REGISTER PIN, x2 internal repeat for counter
// capture — idempotent). The asm round-trip makes wf values opaque so the
// compiler cannot rematerialize them from W1T inside the MFMA loop.
// ---------------------------------------------------------------------------
__global__ __launch_bounds__(256, 2) void precompute_P(
    const float* __restrict__ node_emb,
    const __half* __restrict__ W1T,
    const float* __restrict__ b1,
    __half* __restrict__ P)
{
    __shared__ float Abuf[2][64 * 128];          // 2 x 32 KB

    const int tid  = threadIdx.x;
    const int w    = tid >> 6;
    const int lane = tid & 63;
    const int lr   = lane & 15;
    const int q    = lane >> 4;

    half8 wf[8][4];
#pragma unroll
    for (int nt = 0; nt < 8; nt++)
#pragma unroll
        for (int ks = 0; ks < 4; ks++)
            wf[nt][ks] = *(const half8*)(W1T + (size_t)(nt * 16 + lr) * 128 + ks * 32 + q * 8);

    // PIN: force wf into resident VGPRs; block rematerialization from memory.
#pragma unroll
    for (int nt = 0; nt < 8; nt++)
#pragma unroll
        for (int ks = 0; ks < 4; ks++) {
            uint4v t = __builtin_bit_cast(uint4v, wf[nt][ks]);
            asm volatile("" : "+v"(t));
            wf[nt][ks] = __builtin_bit_cast(half8, t);
        }

    float bias_[4][4];
#pragma unroll
    for (int nt = 0; nt < 4; nt++) {
        const float4 b4 = *(const float4*)(b1 + nt * 16 + q * 4);
        bias_[nt][0] = b4.x; bias_[nt][1] = b4.y;
        bias_[nt][2] = b4.z; bias_[nt][3] = b4.w;
    }

    const int r8   = tid >> 5;
    const int in16 = (tid & 31) << 4;
    const char* nb = (const char*)node_emb;

    for (int rep = 0; rep < 2; rep++) {          // DIAGNOSTIC repeat
        int c = (int)blockIdx.x;
#pragma unroll
        for (int r = 0; r < 8; r++) {
            int row_in = r * 8 + r8;
            int grow = c * 64 + row_in;
            if (grow >= N_NODES) grow = N_NODES - 1;
            const size_t src = (size_t)grow * 512 + (size_t)(in16 ^ ((row_in & 7) << 4));
            gload_lds16(nb + src, (char*)&Abuf[0][0] + (r * 4096 + tid * 16));
        }

        int cur = 0;
        for (; c < NCHUNK; c += (int)gridDim.x, cur ^= 1) {
            const int cnext = c + (int)gridDim.x;
            if (cnext < NCHUNK) {
#pragma unroll
                for (int r = 0; r < 8; r++) {
                    int row_in = r * 8 + r8;
                    int grow = cnext * 64 + row_in;
                    if (grow >= N_NODES) grow = N_NODES - 1;
                    const size_t src = (size_t)grow * 512 + (size_t)(in16 ^ ((row_in & 7) << 4));
                    gload_lds16(nb + src, (char*)&Abuf[cur ^ 1][0] + (r * 4096 + tid * 16));
                }
                asm volatile("s_waitcnt vmcnt(8)" ::: "memory");
            } else {
                asm volatile("s_waitcnt vmcnt(0)" ::: "memory");
            }
            __builtin_amdgcn_s_barrier();

            floatx4 acc[8];
#pragma unroll
            for (int nt = 0; nt < 8; nt++) acc[nt] = (floatx4){0.f, 0.f, 0.f, 0.f};

            const char* Ab = (const char*)&Abuf[cur][0];
            const int rb = w * 16 + lr;
            const int sw = (rb & 7) << 4;
#pragma unroll
            for (int ks = 0; ks < 4; ks++) {
                const int cb = ks * 128 + q * 32;
                const float4 x0 = *(const float4*)(Ab + rb * 512 + ((cb)      ^ sw));
                const float4 x1 = *(const float4*)(Ab + rb * 512 + ((cb + 16) ^ sw));
                half8 af;
                af[0] = (_Float16)x0.x; af[1] = (_Float16)x0.y;
                af[2] = (_Float16)x0.z; af[3] = (_Float16)x0.w;
                af[4] = (_Float16)x1.x; af[5] = (_Float16)x1.y;
                af[6] = (_Float16)x1.z; af[7] = (_Float16)x1.w;
#pragma unroll
                for (int nt = 0; nt < 8; nt++)
                    acc[nt] = __builtin_amdgcn_mfma_f32_16x16x32_f16(wf[nt][ks], af, acc[nt], 0, 0, 0);
            }

            const int grow = c * 64 + w * 16 + lr;
            if (grow < N_NODES) {
                char* prow = (char*)P + (size_t)grow * 256;
#pragma unroll
                for (int m = 0; m < 4; m++) {
                    half8 hh;
#pragma unroll
                    for (int i = 0; i < 4; i++) {
                        float va = acc[2 * m][i];
                        float vb = acc[2 * m + 1][i];
                        if (m < 2) { va += bias_[2 * m][i]; vb += bias_[2 * m + 1][i]; }
                        hh[i]     = (_Float16)va;
                        hh[i + 4] = (_Float16)vb;
                    }
                    *(half8*)(prow + m * 64 + q * 16) = hh;
                }
            }
            __builtin_amdgcn_s_barrier();
        }
    }
}

// ---------------------------------------------------------------------------
__device__ inline bool detect_int64(const int* e32) {
    int orv = 0;
#pragma unroll
    for (int k = 0; k < 8; k++) orv |= e32[2 * k + 1];
    return orv == 0;
}

// ---------------------------------------------------------------------------
// Kernel 2 (R5 version, single launch): quarter-wave per edge, permuted W2.
// ---------------------------------------------------------------------------
__global__ __launch_bounds__(256) void edge_mlp(
    const __half* __restrict__ P,
    const void* __restrict__ eidx_raw,
    const float* __restrict__ W2,
    const float* __restrict__ b2,
    float* __restrict__ out)
{
    const int* e32 = (const int*)eidx_raw;
    const long long* e64 = (const long long*)eidx_raw;
    const bool is64 = detect_int64(e32);

    const int tid  = threadIdx.x;
    const int lane = tid & 63;
    const int j    = lane & 15;
    const int grp  = lane >> 4;
    const int hbase = ((j >> 3) << 5) + ((j & 1) << 4) + (((j >> 1) & 3) << 2);
    const float4 w2 = *(const float4*)(W2 + hbase);
    const float b2v = b2[0];

    const int gwid   = (int)((blockIdx.x * blockDim.x + tid) >> 6);
    const int nwaves = (int)((gridDim.x * blockDim.x) >> 6);

    const half4v zero = {(_Float16)0, (_Float16)0, (_Float16)0, (_Float16)0};

    for (int base = gwid * 16; base < N_EDGES; base += nwaves * 16) {
        int s[4], d[4];
#pragma unroll
        for (int u = 0; u < 4; u++) {
            const int e = base + 4 * u + grp;
            if (is64) { s[u] = (int)e64[e]; d[u] = (int)e64[N_EDGES + e]; }
            else      { s[u] = e32[e];      d[u] = e32[N_EDGES + e]; }
        }
        half4v av[4], bv[4];
#pragma unroll
        for (int u = 0; u < 4; u++) {
            av[u] = *(const half4v*)(P + (size_t)s[u] * 128 + 4 * j);
            bv[u] = *(const half4v*)(P + (size_t)d[u] * 128 + 64 + 4 * j);
        }
#pragma unroll
        for (int u = 0; u < 4; u++) {
            const half4v t = av[u] + bv[u];
            const half4v r = __builtin_elementwise_max(t, zero);
            float acc = (float)r[0] * w2.x + (float)r[1] * w2.y
                      + (float)r[2] * w2.z + (float)r[3] * w2.w;
#pragma unroll
            for (int off = 8; off >= 1; off >>= 1)
                acc += __shfl_xor(acc, off, 64);
            if (j == 0) out[base + 4 * u + grp] = acc + b2v;
        }
    }
}

// ---------------------------------------------------------------------------
// Fallback (ws too small): direct per-edge compute, slow but correct.
// ---------------------------------------------------------------------------
__global__ __launch_bounds__(256) void edge_mlp_direct(
    const float* __restrict__ node_emb,
    const void* __restrict__ eidx_raw,
    const float* __restrict__ W1,
    const float* __restrict__ b1,
    const float* __restrict__ W2,
    const float* __restrict__ b2,
    float* __restrict__ out)
{
    const int* e32 = (const int*)eidx_raw;
    const long long* e64 = (const long long*)eidx_raw;
    const bool is64 = detect_int64(e32);

    const int lane = threadIdx.x & 63;
    const float w2  = W2[lane];
    const float b2v = b2[0];
    const int gwid   = (int)((blockIdx.x * blockDim.x + threadIdx.x) >> 6);
    const int nwaves = (int)((gridDim.x * blockDim.x) >> 6);

    for (int e = gwid; e < N_EDGES; e += nwaves) {
        int s, d;
        if (is64) { s = (int)e64[e]; d = (int)e64[N_EDGES + e]; }
        else      { s = e32[e];      d = e32[N_EDGES + e]; }
        const float* es = node_emb + (size_t)s * DIM;
        const float* ed = node_emb + (size_t)d * DIM;
        float acc = b1[lane];
        for (int k = 0; k < DIM; k++) {
            acc += es[k] * W1[k * HID + lane];
            acc += ed[k] * W1[(DIM + k) * HID + lane];
        }
        float t = fmaxf(acc, 0.f) * w2;
#pragma unroll
        for (int off = 32; off >= 1; off >>= 1)
            t += __shfl_xor(t, off, 64);
        if (lane == 0) out[e] = t + b2v;
    }
}

// ---------------------------------------------------------------------------
// COUNTER-CAPTURE: precompute_P x2 internal repeat (idempotent) so its
// dispatch exceeds the ~40us fillBuffer cutoff and appears in top-5 WITH
// counters (VGPR_Count answers the remat question). edge_mlp back to single.
// ---------------------------------------------------------------------------
extern "C" void kernel_launch(void* const* d_in, const int* in_sizes, int n_in,
                              void* d_out, int out_size, void* d_ws, size_t ws_size,
                              hipStream_t stream) {
    const float* node_emb = (const float*)d_in[0];
    const void*  eidx     = d_in[1];
    const float* W1       = (const float*)d_in[2];
    const float* b1       = (const float*)d_in[3];
    const float* W2       = (const float*)d_in[4];
    const float* b2       = (const float*)d_in[5];
    float* out = (float*)d_out;

    const size_t wt_off = 32u * 1024 * 1024;
    const size_t need   = wt_off + 128 * 128 * sizeof(__half);

    if (ws_size >= need) {
        __half* P   = (__half*)d_ws;
        __half* W1T = (__half*)((char*)d_ws + wt_off);
        prep_W<<<32, 256, 0, stream>>>(W1, W1T);
        precompute_P<<<512, 256, 0, stream>>>(node_emb, W1T, b1, P);
        edge_mlp<<<2048, 256, 0, stream>>>(P, eidx, W2, b2, out);
    } else {
        edge_mlp_direct<<<4096, 256, 0, stream>>>(node_emb, eidx, W1, b1, W2, b2, out);
    }
}